// Round 9
// baseline (1847.661 us; speedup 1.0000x reference)
//
#include <hip/hip_runtime.h>

typedef float floatx4 __attribute__((ext_vector_type(4)));
typedef long longx2 __attribute__((ext_vector_type(2)));
typedef unsigned int u32;
typedef unsigned char u8;

#define MDIM 4096
#define HDIM 4096
#define IDIM 14336
#define FP8MAX 448.0f

// ---------------------------------------------------------------------------
// LDS tile geometry (BK-half=64): rows x 64 B. 16B chunk c of row r lives at
// slot (c ^ swz4(r)); global_load_lds writes LINEARLY so the per-lane GLOBAL
// source is pre-swizzled (both-sides-or-neither). Ring-3 buffers, runtime cb
// (literal-unroll spilled: R6). 512-thread blocks, 8 waves x 32 rows:
// BM=256 halves staged bytes/MFMA vs the 128-tile (R8 limiter).
// ---------------------------------------------------------------------------
__device__ __forceinline__ int swz4(int r) { return (r ^ (r >> 2)) & 3; }
__device__ __forceinline__ int frag_off(int row, int quad) {
  return (row << 6) + ((quad ^ swz4(row)) << 4);
}

__device__ __forceinline__ void gload16(const u8* g, u8* l) {
  __builtin_amdgcn_global_load_lds((const __attribute__((address_space(1))) u32*)g,
                                   (__attribute__((address_space(3))) u32*)l, 16, 0, 0);
}

#define VMW(n) asm volatile("s_waitcnt vmcnt(" #n ")" ::: "memory")
#define BAR() __builtin_amdgcn_s_barrier()

// ---------------------------------------------------------------------------
// Weight-dtype detection: 2 = fp32, 1 = bf16, 0 = raw fp8 bytes.
// ---------------------------------------------------------------------------
__global__ void detect_dtype(const unsigned int* __restrict__ w, int* __restrict__ flag) {
  if (threadIdx.x == 0 && blockIdx.x == 0) {
    bool f32 = true, b16 = true;
    for (int i = 0; i < 64; ++i) {
      const unsigned int v = w[i];
      if (v & 0xFFFFFu) f32 = false;
      if ((v & 0xFu) || ((v >> 16) & 0xFu)) b16 = false;
    }
    *flag = f32 ? 2 : (b16 ? 1 : 0);
  }
}

__device__ __forceinline__ float bfu(unsigned int bits16) {
  union { unsigned int u; float f; } c;
  c.u = bits16 << 16;
  return c.f;
}

__device__ __forceinline__ unsigned int pack2(unsigned int lo, unsigned int hi) {
  int pk = __builtin_amdgcn_cvt_pk_fp8_f32(bfu(lo & 0xFFFFu), bfu(lo >> 16), 0, false);
  pk = __builtin_amdgcn_cvt_pk_fp8_f32(bfu(hi & 0xFFFFu), bfu(hi >> 16), pk, true);
  return (unsigned int)pk;
}

__global__ __launch_bounds__(256) void conv_w(const void* __restrict__ src,
                                              unsigned char* __restrict__ dst,
                                              const int* __restrict__ flag_p) {
  const int flag = *flag_p;
  if (flag == 0) return;
  const long t = (long)blockIdx.x * 256 + threadIdx.x;  // 16 elements per thread
  uint4 out;
  if (flag == 2) {
    const float4* s = (const float4*)src;
    unsigned int o[4];
#pragma unroll
    for (int p = 0; p < 4; ++p) {
      const float4 v = s[t * 4 + p];
      int pk = __builtin_amdgcn_cvt_pk_fp8_f32(v.x, v.y, 0, false);
      pk = __builtin_amdgcn_cvt_pk_fp8_f32(v.z, v.w, pk, true);
      o[p] = (unsigned int)pk;
    }
    out = make_uint4(o[0], o[1], o[2], o[3]);
  } else {
    const uint4* s = (const uint4*)src;
    const uint4 a = s[t * 2], b = s[t * 2 + 1];
    out = make_uint4(pack2(a.x, a.y), pack2(a.z, a.w),
                     pack2(b.x, b.y), pack2(b.z, b.w));
  }
  ((uint4*)dst)[t] = out;
}

// ---------------------------------------------------------------------------
// Kernel 1: fake-quant activations. One wave per (row, 128-col group).
// ---------------------------------------------------------------------------
__global__ __launch_bounds__(256) void fq_act(const float* __restrict__ x,
                                              unsigned char* __restrict__ xq,
                                              float* __restrict__ xsT) {
  const int tid = threadIdx.x;
  const int lane = tid & 63, w = tid >> 6;
  const int g = blockIdx.x * 4 + w;
  const int row = g >> 5, kb = g & 31;

  const float2 v = ((const float2*)(x + (size_t)row * HDIM + kb * 128))[lane];
  float amax = fmaxf(fabsf(v.x), fabsf(v.y));
#pragma unroll
  for (int off = 1; off < 64; off <<= 1)
    amax = fmaxf(amax, __shfl_xor(amax, off, 64));

  const float scale = fmaxf(amax / FP8MAX, 1e-12f);
  const float q0 = fminf(fmaxf(v.x / scale, -FP8MAX), FP8MAX);
  const float q1 = fminf(fmaxf(v.y / scale, -FP8MAX), FP8MAX);
  const int pk = __builtin_amdgcn_cvt_pk_fp8_f32(q0, q1, 0, false);
  ((unsigned short*)(xq + (size_t)row * HDIM + kb * 128))[lane] = (unsigned short)(pk & 0xFFFF);
  if (lane == 0) xsT[(size_t)kb * MDIM + row] = scale;
}

// ---------------------------------------------------------------------------
// Kernel 2: fused gate/up blockwise-fp8 GEMM + silu*u + per-row-128 fake quant.
// BM=256 x BN=128, 512 threads (8 waves x 32 rows, acc 128 AGPR/wave).
// Ring-3 x (A 16K | G 8K | U 8K) = 96 KB. Staged bytes/CU/kb: 96 -> 64 KB.
// ---------------------------------------------------------------------------
__global__ __launch_bounds__(512, 2)
void dual_gemm_silu_fq(const u8* __restrict__ xq, const float* __restrict__ xsT,
                       const u8* __restrict__ gw_cv, const u8* __restrict__ gw_raw,
                       const float* __restrict__ gs,
                       const u8* __restrict__ uw_cv, const u8* __restrict__ uw_raw,
                       const float* __restrict__ us,
                       u8* __restrict__ hq, float* __restrict__ hsT,
                       const int* __restrict__ flag_p, const int use_conv) {
  __shared__ __align__(16) u8 lds[98304];

  const int tid = threadIdx.x;
  const int lane = tid & 63, wid = tid >> 6;       // wid 0..7
  const int quad = lane >> 4, l16 = lane & 15;

  // XCD-chunked swizzle: 1792 = 8 * 224 (bijective).
  const int bid0 = blockIdx.x;
  const int bid = (bid0 & 7) * 224 + (bid0 >> 3);
  const int mi = bid & 15, ni = bid >> 4;          // mi 0..15, ni 0..111
  const size_t m0 = (size_t)mi << 8, n0 = (size_t)ni << 7;

  const u8* gw = gw_raw;
  const u8* uw = uw_raw;
  if (use_conv) {
    if (*flag_p != 0) { gw = gw_cv; uw = uw_cv; }
  }

  const u8* baseA = xq + m0 * HDIM;
  const u8* baseG = gw + n0 * HDIM;
  const u8* baseU = uw + n0 * HDIM;

  // staging: A 16 KB (256 rows) = 2 loads/thread, G/U 8 KB (128 rows) = 1 each
  const int srow = tid >> 2, slot = tid & 3;
  u32 srcA[2], dstA[2];
#pragma unroll
  for (int p = 0; p < 2; ++p) {
    const int row = p * 128 + srow;
    srcA[p] = (u32)(row * HDIM) + (u32)((slot ^ swz4(row)) << 4);
    dstA[p] = (u32)(p * 8192 + tid * 16);
  }
  const u32 srcW = (u32)(srow * HDIM) + (u32)((slot ^ swz4(srow)) << 4);
  const u32 dstW = (u32)(tid * 16);

  int offA[2], offB[8];
#pragma unroll
  for (int mt = 0; mt < 2; ++mt) offA[mt] = frag_off(wid * 32 + mt * 16 + l16, quad);
#pragma unroll
  for (int nt = 0; nt < 8; ++nt) offB[nt] = frag_off(nt * 16 + l16, quad);

  floatx4 accG[2][8], accU[2][8];
#pragma unroll
  for (int mt = 0; mt < 2; ++mt)
#pragma unroll
    for (int nt = 0; nt < 8; ++nt) {
      accG[mt][nt] = {0.f, 0.f, 0.f, 0.f};
      accU[mt][nt] = {0.f, 0.f, 0.f, 0.f};
    }

  auto STAGE = [&](int t, int b) {
    const u32 ko = (u32)t << 6;
    u8* lb = lds + b * 32768;
    gload16(baseA + srcA[0] + ko, lb + dstA[0]);
    gload16(baseA + srcA[1] + ko, lb + dstA[1]);
    gload16(baseG + srcW + ko, lb + 16384u + dstW);
    gload16(baseU + srcW + ko, lb + 24576u + dstW);
  };

  auto HALF = [&](int b) {
    const u8* lb = lds + b * 32768;
    const u8* bufA = lb;
    const u8* bufG = lb + 16384;
    const u8* bufU = lb + 24576;
    longx2 aF[2];
#pragma unroll
    for (int mt = 0; mt < 2; ++mt) aF[mt] = *(const longx2*)(bufA + offA[mt]);

    __builtin_amdgcn_s_setprio(1);
#pragma unroll
    for (int nt = 0; nt < 8; ++nt) {
      const longx2 bF = *(const longx2*)(bufG + offB[nt]);
#pragma unroll
      for (int mt = 0; mt < 2; ++mt) {
        accG[mt][nt] = __builtin_amdgcn_mfma_f32_16x16x32_fp8_fp8(aF[mt][0], bF[0], accG[mt][nt], 0, 0, 0);
        accG[mt][nt] = __builtin_amdgcn_mfma_f32_16x16x32_fp8_fp8(aF[mt][1], bF[1], accG[mt][nt], 0, 0, 0);
      }
    }
#pragma unroll
    for (int nt = 0; nt < 8; ++nt) {
      const longx2 bF = *(const longx2*)(bufU + offB[nt]);
#pragma unroll
      for (int mt = 0; mt < 2; ++mt) {
        accU[mt][nt] = __builtin_amdgcn_mfma_f32_16x16x32_fp8_fp8(aF[mt][0], bF[0], accU[mt][nt], 0, 0, 0);
        accU[mt][nt] = __builtin_amdgcn_mfma_f32_16x16x32_fp8_fp8(aF[mt][1], bF[1], accU[mt][nt], 0, 0, 0);
      }
    }
    __builtin_amdgcn_s_setprio(0);
  };

  // scale prefetch state (one kb ahead)
  const float* xsBase = xsT + m0 + wid * 32 + quad * 4;
  floatx4 xv0 = *(const floatx4*)(xsBase);
  floatx4 xv1 = *(const floatx4*)(xsBase + 16);
  float sgn = gs[ni * 32];
  float sun = us[ni * 32];

  STAGE(0, 0);
  STAGE(1, 1);

  floatx4 prX[2];
  float sgp = 1.f, sup = 1.f;
  int cb = 0;

  for (int kb = 0; kb < 32; ++kb) {
    // ---- half 1 (consume t = 2kb) ----
    {
      int sb = cb + 2; if (sb >= 3) sb -= 3;
      if (kb < 31) STAGE(2 * kb + 2, sb);
      // rescale under the in-flight stage DMA
      const floatx4 cx0 = xv0, cx1 = xv1;
      const float sgc = sgn, suc = sun;
      if (kb) {
        const float rgs = sgp * __builtin_amdgcn_rcpf(sgc);
        const float rus = sup * __builtin_amdgcn_rcpf(suc);
        floatx4 i0, i1;
#pragma unroll
        for (int r = 0; r < 4; ++r) {
          i0[r] = __builtin_amdgcn_rcpf(cx0[r]);
          i1[r] = __builtin_amdgcn_rcpf(cx1[r]);
        }
        const floatx4 cm0 = prX[0] * i0, cm1 = prX[1] * i1;
        const floatx4 rg0 = cm0 * rgs, ru0 = cm0 * rus;
        const floatx4 rg1 = cm1 * rgs, ru1 = cm1 * rus;
#pragma unroll
        for (int nt = 0; nt < 8; ++nt) {
          accG[0][nt] *= rg0;
          accG[1][nt] *= rg1;
          accU[0][nt] *= ru0;
          accU[1][nt] *= ru1;
        }
      }
      prX[0] = cx0; prX[1] = cx1;
      sgp = sgc; sup = suc;
      const int kbn = kb < 31 ? kb + 1 : 31;
      const float* xn = xsBase + (size_t)kbn * MDIM;
      xv0 = *(const floatx4*)(xn);
      xv1 = *(const floatx4*)(xn + 16);
      sgn = gs[ni * 32 + kbn];
      sun = us[ni * 32 + kbn];

      if (kb < 31) { VMW(12); } else { VMW(8); }
      BAR();
      HALF(cb);
      BAR();
      if (++cb >= 3) cb = 0;
    }
    // ---- half 2 (consume t = 2kb+1) ----
    {
      int sb = cb + 2; if (sb >= 3) sb -= 3;
      if (kb < 31) {
        STAGE(2 * kb + 3, sb);
        VMW(12);
      } else {
        VMW(0);
      }
      BAR();
      HALF(cb);
      BAR();
      if (++cb >= 3) cb = 0;
    }
  }

  // undo running-scale
#pragma unroll
  for (int mt = 0; mt < 2; ++mt) {
    const floatx4 fg = prX[mt] * sgp;
    const floatx4 fu = prX[mt] * sup;
#pragma unroll
    for (int nt = 0; nt < 8; ++nt) {
      accG[mt][nt] *= fg;
      accU[mt][nt] *= fu;
    }
  }

  // ---- epilogue: h = silu(g)*u, per-row fake quant over this 128-col group.
  // Stage bytes into LDS (row-major [256][128] = 32 KB) then store coalesced.
  u8* ot = lds;  // safe: all waves past final barrier
#pragma unroll
  for (int mt = 0; mt < 2; ++mt) {
    float h[8][4];
    float amax[4] = {0.f, 0.f, 0.f, 0.f};
#pragma unroll
    for (int nt = 0; nt < 8; ++nt)
#pragma unroll
      for (int r = 0; r < 4; ++r) {
        const float gv = accG[mt][nt][r];
        const float uv = accU[mt][nt][r];
        const float hv = (gv / (1.f + __expf(-gv))) * uv;
        h[nt][r] = hv;
        amax[r] = fmaxf(amax[r], fabsf(hv));
      }
#pragma unroll
    for (int off = 1; off < 16; off <<= 1)
#pragma unroll
      for (int r = 0; r < 4; ++r)
        amax[r] = fmaxf(amax[r], __shfl_xor(amax[r], off, 64));

    float scale[4];
#pragma unroll
    for (int r = 0; r < 4; ++r) scale[r] = fmaxf(amax[r] / FP8MAX, 1e-12f);

    const int rowl = wid * 32 + mt * 16 + quad * 4;
    if (l16 == 0) {
#pragma unroll
      for (int r = 0; r < 4; ++r)
        hsT[(size_t)ni * MDIM + m0 + rowl + r] = scale[r];
    }
#pragma unroll
    for (int nt = 0; nt < 8; ++nt)
#pragma unroll
      for (int r = 0; r < 4; ++r) {
        const float q = fminf(fmaxf(h[nt][r] / scale[r], -FP8MAX), FP8MAX);
        const int pk = __builtin_amdgcn_cvt_pk_fp8_f32(q, 0.f, 0, false);
        ot[(rowl + r) * 128 + nt * 16 + l16] = (u8)(pk & 0xFF);
      }
  }
  __syncthreads();
  {
    const int row = tid >> 1, half = tid & 1;      // rows 0..255
    const uint4* s = (const uint4*)(ot + row * 128 + half * 64);
    uint4* d = (uint4*)(hq + (m0 + row) * IDIM + n0 + half * 64);
#pragma unroll
    for (int i = 0; i < 4; ++i) d[i] = s[i];
  }
}

// ---------------------------------------------------------------------------
// Kernel 3: down projection. BM=256 x BN=256, 512 threads (8 waves x 32 rows,
// nt=16 spanning two 128-col scale blocks). Ring-3 x (A 16K | B 16K) = 96 KB.
// Bytes/MFMA: 128 -> 64. Grid = 256 blocks = 1/CU.
// ---------------------------------------------------------------------------
__global__ __launch_bounds__(512, 2)
void gemm_down(const u8* __restrict__ hq, const float* __restrict__ hsT,
               const u8* __restrict__ dw_cv, const u8* __restrict__ dw_raw,
               const float* __restrict__ dsc, float* __restrict__ out,
               const int* __restrict__ flag_p, const int use_conv) {
  __shared__ __align__(16) u8 lds[98304];

  const int tid = threadIdx.x;
  const int lane = tid & 63, wid = tid >> 6;
  const int quad = lane >> 4, l16 = lane & 15;

  // 256 = 8 * 32 (bijective)
  const int bid0 = blockIdx.x;
  const int bid = (bid0 & 7) * 32 + (bid0 >> 3);
  const int mi = bid & 15, ni = bid >> 4;          // mi 0..15, ni 0..15
  const size_t m0 = (size_t)mi << 8, n0 = (size_t)ni << 8;

  const u8* dw = dw_raw;
  if (use_conv) {
    if (*flag_p != 0) dw = dw_cv;
  }

  const u8* baseA = hq + m0 * IDIM;
  const u8* baseB = dw + n0 * IDIM;

  // staging: A and B each 16 KB (256 rows x 64 B) = 2 loads/thread each
  const int srow = tid >> 2, slot = tid & 3;
  u32 srcR[2], dstR[2];
#pragma unroll
  for (int p = 0; p < 2; ++p) {
    const int row = p * 128 + srow;
    srcR[p] = (u32)(row * IDIM) + (u32)((slot ^ swz4(row)) << 4);
    dstR[p] = (u32)(p * 8192 + tid * 16);
  }

  int offA[2], offB[16];
#pragma unroll
  for (int mt = 0; mt < 2; ++mt) offA[mt] = frag_off(wid * 32 + mt * 16 + l16, quad);
#pragma unroll
  for (int nt = 0; nt < 16; ++nt) offB[nt] = frag_off(nt * 16 + l16, quad);

  floatx4 acc[2][16];
#pragma unroll
  for (int mt = 0; mt < 2; ++mt)
#pragma unroll
    for (int nt = 0; nt < 16; ++nt) acc[mt][nt] = {0.f, 0.f, 0.f, 0.f};

  auto STAGE = [&](int t, int b) {
    const u32 ko = (u32)t << 6;
    u8* lb = lds + b * 32768;
    gload16(baseA + srcR[0] + ko, lb + dstR[0]);
    gload16(baseA + srcR[1] + ko, lb + dstR[1]);
    gload16(baseB + srcR[0] + ko, lb + 16384u + dstR[0]);
    gload16(baseB + srcR[1] + ko, lb + 16384u + dstR[1]);
  };

  auto HALF = [&](int b) {
    const u8* lb = lds + b * 32768;
    const u8* bufB = lb + 16384;
    longx2 aF[2];
#pragma unroll
    for (int mt = 0; mt < 2; ++mt) aF[mt] = *(const longx2*)(lb + offA[mt]);
    __builtin_amdgcn_s_setprio(1);
#pragma unroll
    for (int nt = 0; nt < 16; ++nt) {
      const longx2 bF = *(const longx2*)(bufB + offB[nt]);
#pragma unroll
      for (int mt = 0; mt < 2; ++mt) {
        acc[mt][nt] = __builtin_amdgcn_mfma_f32_16x16x32_fp8_fp8(aF[mt][0], bF[0], acc[mt][nt], 0, 0, 0);
        acc[mt][nt] = __builtin_amdgcn_mfma_f32_16x16x32_fp8_fp8(aF[mt][1], bF[1], acc[mt][nt], 0, 0, 0);
      }
    }
    __builtin_amdgcn_s_setprio(0);
  };

  const float* hsBase = hsT + m0 + wid * 32 + quad * 4;
  floatx4 xv0 = *(const floatx4*)(hsBase);
  floatx4 xv1 = *(const floatx4*)(hsBase + 16);
  float sdn0 = dsc[(2 * ni) * 112];
  float sdn1 = dsc[(2 * ni + 1) * 112];

  STAGE(0, 0);
  STAGE(1, 1);

  floatx4 prX[2];
  float sd0p = 1.f, sd1p = 1.f;
  int cb = 0;

  for (int kb = 0; kb < 112; ++kb) {
    // ---- half 1 ----
    {
      int sb = cb + 2; if (sb >= 3) sb -= 3;
      if (kb < 111) STAGE(2 * kb + 2, sb);
      const floatx4 cx0 = xv0, cx1 = xv1;
      const float sd0c = sdn0, sd1c = sdn1;
      if (kb) {
        const float rd0 = sd0p * __builtin_amdgcn_rcpf(sd0c);
        const float rd1 = sd1p * __builtin_amdgcn_rcpf(sd1c);
        floatx4 i0, i1;
#pragma unroll
        for (int r = 0; r < 4; ++r) {
          i0[r] = __builtin_amdgcn_rcpf(cx0[r]);
          i1[r] = __builtin_amdgcn_rcpf(cx1[r]);
        }
        const floatx4 cm0 = prX[0] * i0, cm1 = prX[1] * i1;
        const floatx4 r00 = cm0 * rd0, r01 = cm0 * rd1;
        const floatx4 r10 = cm1 * rd0, r11 = cm1 * rd1;
#pragma unroll
      for (int nt = 0; nt < 8; ++nt) {
          acc[0][nt] *= r00;
          acc[1][nt] *= r10;
          acc[0][nt + 8] *= r01;
          acc[1][nt + 8] *= r11;
        }
      }
      prX[0] = cx0; prX[1] = cx1;
      sd0p = sd0c; sd1p = sd1c;
      const int kbn = kb < 111 ? kb + 1 : 111;
      const float* xn = hsBase + (size_t)kbn * MDIM;
      xv0 = *(const floatx4*)(xn);
      xv1 = *(const floatx4*)(xn + 16);
      sdn0 = dsc[(2 * ni) * 112 + kbn];
      sdn1 = dsc[(2 * ni + 1) * 112 + kbn];

      if (kb < 111) { VMW(12); } else { VMW(8); }
      BAR();
      HALF(cb);
      BAR();
      if (++cb >= 3) cb = 0;
    }
    // ---- half 2 ----
    {
      int sb = cb + 2; if (sb >= 3) sb -= 3;
      if (kb < 111) {
        STAGE(2 * kb + 3, sb);
        VMW(12);
      } else {
        VMW(0);
      }
      BAR();
      HALF(cb);
      BAR();
      if (++cb >= 3) cb = 0;
    }
  }

#pragma unroll
  for (int mt = 0; mt < 2; ++mt) {
    const int rowl = wid * 32 + mt * 16 + quad * 4;
#pragma unroll
    for (int nt = 0; nt < 16; ++nt) {
      const float sdf = (nt < 8) ? sd0p : sd1p;
#pragma unroll
      for (int r = 0; r < 4; ++r)
        out[(m0 + rowl + r) * (size_t)HDIM + n0 + nt * 16 + l16] =
            acc[mt][nt][r] * prX[mt][r] * sdf;
    }
  }
}

// ---------------------------------------------------------------------------
extern "C" void kernel_launch(void* const* d_in, const int* in_sizes, int n_in,
                              void* d_out, int out_size, void* d_ws, size_t ws_size,
                              hipStream_t stream) {
  const float* x   = (const float*)d_in[0];
  const void* gw_s = d_in[1];
  const float* gs  = (const float*)d_in[2];
  const void* uw_s = d_in[3];
  const float* us  = (const float*)d_in[4];
  const void* dw_s = d_in[5];
  const float* dsc = (const float*)d_in[6];
  float* out       = (float*)d_out;

  const size_t NW = (size_t)IDIM * HDIM;  // 58,720,256 elements per weight

  unsigned char* ws = (unsigned char*)d_ws;
  unsigned char* xq = ws;                         // 16 MB
  float* xsT = (float*)(ws + 16777216);           // 512 KB
  unsigned char* hq  = ws + 17301504;             // 56 MB
  float* hsT = (float*)(ws + 76021760);           // 1.75 MB
  unsigned char* gwq = ws + 77856768;             // 56 MB
  unsigned char* uwq = ws + 136577024;            // 56 MB
  unsigned char* dwq = gwq;                       // reuse gate slot after dual_gemm
  int* flag = (int*)(ws + 195297280);

  const bool fits = ws_size >= (size_t)195297284;
  const int use_conv = fits ? 1 : 0;

  const int convBlocks = (int)(NW / (16 * 256));  // 14336, exact

  if (fits) {
    detect_dtype<<<1, 64, 0, stream>>>((const unsigned int*)gw_s, flag);
    conv_w<<<convBlocks, 256, 0, stream>>>(gw_s, gwq, flag);
    conv_w<<<convBlocks, 256, 0, stream>>>(uw_s, uwq, flag);
  }
  fq_act<<<(MDIM * (HDIM / 128)) / 4, 256, 0, stream>>>(x, xq, xsT);
  dual_gemm_silu_fq<<<(MDIM / 256) * (IDIM / 128), 512, 0, stream>>>(
      xq, xsT, gwq, (const unsigned char*)gw_s, gs,
      uwq, (const unsigned char*)uw_s, us, hq, hsT, flag, use_conv);
  if (fits) {
    conv_w<<<convBlocks, 256, 0, stream>>>(dw_s, dwq, flag);
  }
  gemm_down<<<(MDIM / 256) * (HDIM / 256), 512, 0, stream>>>(
      hq, hsT, dwq, (const unsigned char*)dw_s, dsc, out, flag, use_conv);
}

// Round 10
// 1754.665 us; speedup vs baseline: 1.0530x; 1.0530x over previous
//
#include <hip/hip_runtime.h>

typedef float floatx4 __attribute__((ext_vector_type(4)));
typedef long longx2 __attribute__((ext_vector_type(2)));
typedef unsigned int u32;
typedef unsigned char u8;

#define MDIM 4096
#define HDIM 4096
#define IDIM 14336
#define FP8MAX 448.0f

// ---------------------------------------------------------------------------
// LDS tile geometry (BK-half=64): rows x 64 B. 16B chunk c of row r lives at
// slot (c ^ swz4(r)); global_load_lds writes LINEARLY (uniform base+lane*16)
// so the per-lane GLOBAL source is pre-swizzled (both-sides-or-neither).
// Ring-3, runtime cb (literal-unroll spilled: R6 = 4 GB scratch).
// R9 lesson: 2 blocks/CU of 4 waves beats 1 block of 8 waves even at 2x the
// HBM traffic -> 128-row tiles + 72KB LDS are the occupancy sweet spot.
// ---------------------------------------------------------------------------
__device__ __forceinline__ int swz4(int r) { return (r ^ (r >> 2)) & 3; }
__device__ __forceinline__ int frag_off(int row, int quad) {
  return (row << 6) + ((quad ^ swz4(row)) << 4);
}

__device__ __forceinline__ void gload16(const u8* g, u8* l) {
  __builtin_amdgcn_global_load_lds((const __attribute__((address_space(1))) u32*)g,
                                   (__attribute__((address_space(3))) u32*)l, 16, 0, 0);
}

#define VMW(n) asm volatile("s_waitcnt vmcnt(" #n ")" ::: "memory")
#define BAR() __builtin_amdgcn_s_barrier()

// ---------------------------------------------------------------------------
// Weight-dtype detection: 2 = fp32, 1 = bf16, 0 = raw fp8 bytes.
// ---------------------------------------------------------------------------
__global__ void detect_dtype(const unsigned int* __restrict__ w, int* __restrict__ flag) {
  if (threadIdx.x == 0 && blockIdx.x == 0) {
    bool f32 = true, b16 = true;
    for (int i = 0; i < 64; ++i) {
      const unsigned int v = w[i];
      if (v & 0xFFFFFu) f32 = false;
      if ((v & 0xFu) || ((v >> 16) & 0xFu)) b16 = false;
    }
    *flag = f32 ? 2 : (b16 ? 1 : 0);
  }
}

__device__ __forceinline__ float bfu(unsigned int bits16) {
  union { unsigned int u; float f; } c;
  c.u = bits16 << 16;
  return c.f;
}

__device__ __forceinline__ unsigned int pack2(unsigned int lo, unsigned int hi) {
  int pk = __builtin_amdgcn_cvt_pk_fp8_f32(bfu(lo & 0xFFFFu), bfu(lo >> 16), 0, false);
  pk = __builtin_amdgcn_cvt_pk_fp8_f32(bfu(hi & 0xFFFFu), bfu(hi >> 16), pk, true);
  return (unsigned int)pk;
}

__global__ __launch_bounds__(256) void conv_w(const void* __restrict__ src,
                                              unsigned char* __restrict__ dst,
                                              const int* __restrict__ flag_p) {
  const int flag = *flag_p;
  if (flag == 0) return;
  const long t = (long)blockIdx.x * 256 + threadIdx.x;  // 16 elements per thread
  uint4 out;
  if (flag == 2) {
    const float4* s = (const float4*)src;
    unsigned int o[4];
#pragma unroll
    for (int p = 0; p < 4; ++p) {
      const float4 v = s[t * 4 + p];
      int pk = __builtin_amdgcn_cvt_pk_fp8_f32(v.x, v.y, 0, false);
      pk = __builtin_amdgcn_cvt_pk_fp8_f32(v.z, v.w, pk, true);
      o[p] = (unsigned int)pk;
    }
    out = make_uint4(o[0], o[1], o[2], o[3]);
  } else {
    const uint4* s = (const uint4*)src;
    const uint4 a = s[t * 2], b = s[t * 2 + 1];
    out = make_uint4(pack2(a.x, a.y), pack2(a.z, a.w),
                     pack2(b.x, b.y), pack2(b.z, b.w));
  }
  ((uint4*)dst)[t] = out;
}

// ---------------------------------------------------------------------------
// Kernel 1: fake-quant activations. One wave per (row, 128-col group).
// ---------------------------------------------------------------------------
__global__ __launch_bounds__(256) void fq_act(const float* __restrict__ x,
                                              unsigned char* __restrict__ xq,
                                              float* __restrict__ xsT) {
  const int tid = threadIdx.x;
  const int lane = tid & 63, w = tid >> 6;
  const int g = blockIdx.x * 4 + w;
  const int row = g >> 5, kb = g & 31;

  const float2 v = ((const float2*)(x + (size_t)row * HDIM + kb * 128))[lane];
  float amax = fmaxf(fabsf(v.x), fabsf(v.y));
#pragma unroll
  for (int off = 1; off < 64; off <<= 1)
    amax = fmaxf(amax, __shfl_xor(amax, off, 64));

  const float scale = fmaxf(amax / FP8MAX, 1e-12f);
  const float q0 = fminf(fmaxf(v.x / scale, -FP8MAX), FP8MAX);
  const float q1 = fminf(fmaxf(v.y / scale, -FP8MAX), FP8MAX);
  const int pk = __builtin_amdgcn_cvt_pk_fp8_f32(q0, q1, 0, false);
  ((unsigned short*)(xq + (size_t)row * HDIM + kb * 128))[lane] = (unsigned short)(pk & 0xFFFF);
  if (lane == 0) xsT[(size_t)kb * MDIM + row] = scale;
}

// ---------------------------------------------------------------------------
// Kernel 2: fused gate/up blockwise-fp8 GEMM + silu*u + per-row-128 fake quant.
// R8-measured best (827 us, MfmaUtil 53): 128x128 tile, 256 thr, ring-3,
// runtime cb, rcp/packed rescale, STG-before-RESC. Verbatim revert.
// ---------------------------------------------------------------------------
__global__ __launch_bounds__(256, 2)
void dual_gemm_silu_fq(const u8* __restrict__ xq, const float* __restrict__ xsT,
                       const u8* __restrict__ gw_cv, const u8* __restrict__ gw_raw,
                       const float* __restrict__ gs,
                       const u8* __restrict__ uw_cv, const u8* __restrict__ uw_raw,
                       const float* __restrict__ us,
                       u8* __restrict__ hq, float* __restrict__ hsT,
                       const int* __restrict__ flag_p, const int use_conv) {
  // 3 ring buffers x (A 8K | G 8K | U 8K); first 16 KB reused for output tile.
  __shared__ __align__(16) u8 lds[73728];

  const int tid = threadIdx.x;
  const int lane = tid & 63, wid = tid >> 6;
  const int quad = lane >> 4, l16 = lane & 15;

  // XCD-chunked swizzle: 3584 = 8 * 448 (bijective).
  const int bid0 = blockIdx.x;
  const int bid = (bid0 & 7) * 448 + (bid0 >> 3);
  const int mi = bid & 31, ni = bid >> 5;
  const size_t m0 = (size_t)mi << 7, n0 = (size_t)ni << 7;

  const u8* gw = gw_raw;
  const u8* uw = uw_raw;
  if (use_conv) {
    if (*flag_p != 0) { gw = gw_cv; uw = uw_cv; }
  }

  const u8* baseA = xq + m0 * HDIM;
  const u8* baseG = gw + n0 * HDIM;
  const u8* baseU = uw + n0 * HDIM;

  const int r16 = lane >> 2, slot = lane & 3;
  u32 srcoff[2], dstoff[2];
#pragma unroll
  for (int i = 0; i < 2; ++i) {
    const int row = wid * 32 + i * 16 + r16;
    srcoff[i] = (u32)(row * HDIM) + (u32)((slot ^ swz4(row)) << 4);
    dstoff[i] = (u32)(wid * 2048 + i * 1024);
  }

  int offA[2], offB[8];
#pragma unroll
  for (int mt = 0; mt < 2; ++mt) offA[mt] = frag_off(wid * 32 + mt * 16 + l16, quad);
#pragma unroll
  for (int nt = 0; nt < 8; ++nt) offB[nt] = frag_off(nt * 16 + l16, quad);

  floatx4 accG[2][8], accU[2][8];
#pragma unroll
  for (int mt = 0; mt < 2; ++mt)
#pragma unroll
    for (int nt = 0; nt < 8; ++nt) {
      accG[mt][nt] = {0.f, 0.f, 0.f, 0.f};
      accU[mt][nt] = {0.f, 0.f, 0.f, 0.f};
    }

  auto STAGE = [&](int t, int b) {
    const u32 ko = (u32)t << 6;
    u8* lb = lds + b * 24576;
#pragma unroll
    for (int i = 0; i < 2; ++i) {
      gload16(baseA + srcoff[i] + ko, lb + dstoff[i]);
      gload16(baseG + srcoff[i] + ko, lb + 8192u + dstoff[i]);
      gload16(baseU + srcoff[i] + ko, lb + 16384u + dstoff[i]);
    }
  };

  auto HALF = [&](int b) {
    const u8* lb = lds + b * 24576;
    const u8* bufA = lb;
    const u8* bufG = lb + 8192;
    const u8* bufU = lb + 16384;
    longx2 aF[2];
#pragma unroll
    for (int mt = 0; mt < 2; ++mt) aF[mt] = *(const longx2*)(bufA + offA[mt]);

    __builtin_amdgcn_s_setprio(1);
#pragma unroll
    for (int nt = 0; nt < 8; ++nt) {
      const longx2 bF = *(const longx2*)(bufG + offB[nt]);
#pragma unroll
      for (int mt = 0; mt < 2; ++mt) {
        accG[mt][nt] = __builtin_amdgcn_mfma_f32_16x16x32_fp8_fp8(aF[mt][0], bF[0], accG[mt][nt], 0, 0, 0);
        accG[mt][nt] = __builtin_amdgcn_mfma_f32_16x16x32_fp8_fp8(aF[mt][1], bF[1], accG[mt][nt], 0, 0, 0);
      }
    }
#pragma unroll
    for (int nt = 0; nt < 8; ++nt) {
      const longx2 bF = *(const longx2*)(bufU + offB[nt]);
#pragma unroll
      for (int mt = 0; mt < 2; ++mt) {
        accU[mt][nt] = __builtin_amdgcn_mfma_f32_16x16x32_fp8_fp8(aF[mt][0], bF[0], accU[mt][nt], 0, 0, 0);
        accU[mt][nt] = __builtin_amdgcn_mfma_f32_16x16x32_fp8_fp8(aF[mt][1], bF[1], accU[mt][nt], 0, 0, 0);
      }
    }
    __builtin_amdgcn_s_setprio(0);
  };

  // scale prefetch state (one kb ahead); 16B-aligned vector loads
  const float* xsBase = xsT + m0 + wid * 32 + quad * 4;
  floatx4 xv0 = *(const floatx4*)(xsBase);
  floatx4 xv1 = *(const floatx4*)(xsBase + 16);
  float sgn = gs[ni * 32];
  float sun = us[ni * 32];

  STAGE(0, 0);
  STAGE(1, 1);

  floatx4 prX[2];
  float sgp = 1.f, sup = 1.f;
  int cb = 0;

  for (int kb = 0; kb < 32; ++kb) {
    // ---- half 1 (consume t = 2kb) ----
    {
      int sb = cb + 2; if (sb >= 3) sb -= 3;
      if (kb < 31) STAGE(2 * kb + 2, sb);
      // rescale under the in-flight stage DMA
      const floatx4 cx0 = xv0, cx1 = xv1;
      const float sgc = sgn, suc = sun;
      if (kb) {
        const float rgs = sgp * __builtin_amdgcn_rcpf(sgc);
        const float rus = sup * __builtin_amdgcn_rcpf(suc);
        floatx4 i0, i1;
#pragma unroll
        for (int r = 0; r < 4; ++r) {
          i0[r] = __builtin_amdgcn_rcpf(cx0[r]);
          i1[r] = __builtin_amdgcn_rcpf(cx1[r]);
        }
        const floatx4 cm0 = prX[0] * i0, cm1 = prX[1] * i1;
        const floatx4 rg0 = cm0 * rgs, ru0 = cm0 * rus;
        const floatx4 rg1 = cm1 * rgs, ru1 = cm1 * rus;
#pragma unroll
        for (int nt = 0; nt < 8; ++nt) {
          accG[0][nt] *= rg0;
          accG[1][nt] *= rg1;
          accU[0][nt] *= ru0;
          accU[1][nt] *= ru1;
        }
      }
      prX[0] = cx0; prX[1] = cx1;
      sgp = sgc; sup = suc;
      const int kbn = kb < 31 ? kb + 1 : 31;
      const float* xn = xsBase + (size_t)kbn * MDIM;
      xv0 = *(const floatx4*)(xn);
      xv1 = *(const floatx4*)(xn + 16);
      sgn = gs[ni * 32 + kbn];
      sun = us[ni * 32 + kbn];

      if (kb < 31) { VMW(12); } else { VMW(6); }
      BAR();
      HALF(cb);
      BAR();
      if (++cb >= 3) cb = 0;
    }
    // ---- half 2 (consume t = 2kb+1) ----
    {
      int sb = cb + 2; if (sb >= 3) sb -= 3;
      if (kb < 31) {
        STAGE(2 * kb + 3, sb);
        VMW(12);
      } else {
        VMW(0);
      }
      BAR();
      HALF(cb);
      BAR();
      if (++cb >= 3) cb = 0;
    }
  }

  // undo running-scale
#pragma unroll
  for (int mt = 0; mt < 2; ++mt) {
    const floatx4 fg = prX[mt] * sgp;
    const floatx4 fu = prX[mt] * sup;
#pragma unroll
    for (int nt = 0; nt < 8; ++nt) {
      accG[mt][nt] *= fg;
      accU[mt][nt] *= fu;
    }
  }

  // ---- epilogue: h = silu(g)*u, per-row fake quant over this 128-col group.
  u8* ot = lds;  // 16 KB, safe: all waves past final barrier
#pragma unroll
  for (int mt = 0; mt < 2; ++mt) {
    float h[8][4];
    float amax[4] = {0.f, 0.f, 0.f, 0.f};
#pragma unroll
    for (int nt = 0; nt < 8; ++nt)
#pragma unroll
      for (int r = 0; r < 4; ++r) {
        const float gv = accG[mt][nt][r];
        const float uv = accU[mt][nt][r];
        const float hv = (gv / (1.f + __expf(-gv))) * uv;
        h[nt][r] = hv;
        amax[r] = fmaxf(amax[r], fabsf(hv));
      }
#pragma unroll
    for (int off = 1; off < 16; off <<= 1)
#pragma unroll
      for (int r = 0; r < 4; ++r)
        amax[r] = fmaxf(amax[r], __shfl_xor(amax[r], off, 64));

    float scale[4];
#pragma unroll
    for (int r = 0; r < 4; ++r) scale[r] = fmaxf(amax[r] / FP8MAX, 1e-12f);

    const int rowl = wid * 32 + mt * 16 + quad * 4;
    if (l16 == 0) {
#pragma unroll
      for (int r = 0; r < 4; ++r)
        hsT[(size_t)ni * MDIM + m0 + rowl + r] = scale[r];
    }
#pragma unroll
    for (int nt = 0; nt < 8; ++nt)
#pragma unroll
      for (int r = 0; r < 4; ++r) {
        const float q = fminf(fmaxf(h[nt][r] / scale[r], -FP8MAX), FP8MAX);
        const int pk = __builtin_amdgcn_cvt_pk_fp8_f32(q, 0.f, 0, false);
        ot[(rowl + r) * 128 + nt * 16 + l16] = (u8)(pk & 0xFF);
      }
  }
  __syncthreads();
  {
    const int row = tid >> 1, half = tid & 1;
    const uint4* s = (const uint4*)(ot + row * 128 + half * 64);
    uint4* d = (uint4*)(hq + (m0 + row) * IDIM + n0 + half * 64);
#pragma unroll
    for (int i = 0; i < 4; ++i) d[i] = s[i];
  }
}

// ---------------------------------------------------------------------------
// Kernel 3: down projection. BM=128 x BN=256, 256 threads (4 waves x 32 rows,
// nt=16 spanning two 128-col scale blocks): HALF = 64 MFMA per barrier-pair
// (2x the old 32 -> amortizes the per-half vmcnt/barrier/rescale cost like
// dual's G+U does). Ring-3 x (A 8K | B 16K) = 72 KB -> 2 blocks/CU.
// Grid 512 = exactly 2/CU.
// ---------------------------------------------------------------------------
__global__ __launch_bounds__(256, 2)
void gemm_down(const u8* __restrict__ hq, const float* __restrict__ hsT,
               const u8* __restrict__ dw_cv, const u8* __restrict__ dw_raw,
               const float* __restrict__ dsc, float* __restrict__ out,
               const int* __restrict__ flag_p, const int use_conv) {
  __shared__ __align__(16) u8 lds[73728];

  const int tid = threadIdx.x;
  const int lane = tid & 63, wid = tid >> 6;
  const int quad = lane >> 4, l16 = lane & 15;

  // 512 = 8 * 64 (bijective)
  const int bid0 = blockIdx.x;
  const int bid = (bid0 & 7) * 64 + (bid0 >> 3);
  const int mi = bid & 31, ni = bid >> 5;          // mi 0..31, ni 0..15
  const size_t m0 = (size_t)mi << 7, n0 = (size_t)ni << 8;

  const u8* dw = dw_raw;
  if (use_conv) {
    if (*flag_p != 0) dw = dw_cv;
  }

  const u8* baseA = hq + m0 * IDIM;
  const u8* baseB = dw + n0 * IDIM;

  // staging (wave-uniform LDS base + lane*16; per-lane pre-swizzled source):
  // A: 128 rows (8 KB) = 2 issues/wave; B: 256 rows (16 KB) = 4 issues/wave.
  const int r16 = lane >> 2, slot = lane & 3;
  u32 srcA[2], srcB[4];
#pragma unroll
  for (int p = 0; p < 2; ++p) {
    const int row = p * 64 + wid * 16 + r16;
    srcA[p] = (u32)(row * IDIM) + (u32)((slot ^ swz4(row)) << 4);
  }
#pragma unroll
  for (int p = 0; p < 4; ++p) {
    const int row = p * 64 + wid * 16 + r16;
    srcB[p] = (u32)(row * IDIM) + (u32)((slot ^ swz4(row)) << 4);
  }

  int offA[2], offB[16];
#pragma unroll
  for (int mt = 0; mt < 2; ++mt) offA[mt] = frag_off(wid * 32 + mt * 16 + l16, quad);
#pragma unroll
  for (int nt = 0; nt < 16; ++nt) offB[nt] = frag_off(nt * 16 + l16, quad);

  floatx4 acc[2][16];
#pragma unroll
  for (int mt = 0; mt < 2; ++mt)
#pragma unroll
    for (int nt = 0; nt < 16; ++nt) acc[mt][nt] = {0.f, 0.f, 0.f, 0.f};

  auto STAGE = [&](int t, int b) {
    const u32 ko = (u32)t << 6;
    u8* lb = lds + b * 24576;
#pragma unroll
    for (int p = 0; p < 2; ++p)
      gload16(baseA + srcA[p] + ko, lb + (u32)(p * 4096 + wid * 1024));
#pragma unroll
    for (int p = 0; p < 4; ++p)
      gload16(baseB + srcB[p] + ko, lb + 8192u + (u32)(p * 4096 + wid * 1024));
  };

  auto HALF = [&](int b) {
    const u8* lb = lds + b * 24576;
    const u8* bufB = lb + 8192;
    longx2 aF[2];
#pragma unroll
    for (int mt = 0; mt < 2; ++mt) aF[mt] = *(const longx2*)(lb + offA[mt]);
    __builtin_amdgcn_s_setprio(1);
#pragma unroll
    for (int nt = 0; nt < 16; ++nt) {
      const longx2 bF = *(const longx2*)(bufB + offB[nt]);
#pragma unroll
      for (int mt = 0; mt < 2; ++mt) {
        acc[mt][nt] = __builtin_amdgcn_mfma_f32_16x16x32_fp8_fp8(aF[mt][0], bF[0], acc[mt][nt], 0, 0, 0);
        acc[mt][nt] = __builtin_amdgcn_mfma_f32_16x16x32_fp8_fp8(aF[mt][1], bF[1], acc[mt][nt], 0, 0, 0);
      }
    }
    __builtin_amdgcn_s_setprio(0);
  };

  const float* hsBase = hsT + m0 + wid * 32 + quad * 4;
  floatx4 xv0 = *(const floatx4*)(hsBase);
  floatx4 xv1 = *(const floatx4*)(hsBase + 16);
  float sdn0 = dsc[(2 * ni) * 112];
  float sdn1 = dsc[(2 * ni + 1) * 112];

  STAGE(0, 0);
  STAGE(1, 1);

  floatx4 prX[2];
  float sd0p = 1.f, sd1p = 1.f;
  int cb = 0;

  for (int kb = 0; kb < 112; ++kb) {
    // ---- half 1 (consume t = 2kb) ----
    {
      int sb = cb + 2; if (sb >= 3) sb -= 3;
      if (kb < 111) STAGE(2 * kb + 2, sb);
      const floatx4 cx0 = xv0, cx1 = xv1;
      const float sd0c = sdn0, sd1c = sdn1;
      if (kb) {
        const float rd0 = sd0p * __builtin_amdgcn_rcpf(sd0c);
        const float rd1 = sd1p * __builtin_amdgcn_rcpf(sd1c);
        floatx4 i0, i1;
#pragma unroll
        for (int r = 0; r < 4; ++r) {
          i0[r] = __builtin_amdgcn_rcpf(cx0[r]);
          i1[r] = __builtin_amdgcn_rcpf(cx1[r]);
        }
        const floatx4 cm0 = prX[0] * i0, cm1 = prX[1] * i1;
        const floatx4 r00 = cm0 * rd0, r01 = cm0 * rd1;
        const floatx4 r10 = cm1 * rd0, r11 = cm1 * rd1;
#pragma unroll
        for (int nt = 0; nt < 8; ++nt) {
          acc[0][nt] *= r00;
          acc[1][nt] *= r10;
          acc[0][nt + 8] *= r01;
          acc[1][nt + 8] *= r11;
        }
      }
      prX[0] = cx0; prX[1] = cx1;
      sd0p = sd0c; sd1p = sd1c;
      const int kbn = kb < 111 ? kb + 1 : 111;
      const float* xn = hsBase + (size_t)kbn * MDIM;
      xv0 = *(const floatx4*)(xn);
      xv1 = *(const floatx4*)(xn + 16);
      sdn0 = dsc[(2 * ni) * 112 + kbn];
      sdn1 = dsc[(2 * ni + 1) * 112 + kbn];

      if (kb == 0) { VMW(8); } else if (kb < 111) { VMW(12); } else { VMW(8); }
      BAR();
      HALF(cb);
      BAR();
      if (++cb >= 3) cb = 0;
    }
    // ---- half 2 (consume t = 2kb+1) ----
    {
      int sb = cb + 2; if (sb >= 3) sb -= 3;
      if (kb < 111) {
        STAGE(2 * kb + 3, sb);
        VMW(12);
      } else {
        VMW(0);
      }
      BAR();
      HALF(cb);
      BAR();
      if (++cb >= 3) cb = 0;
    }
  }

#pragma unroll
  for (int mt = 0; mt < 2; ++mt) {
    const int rowl = wid * 32 + mt * 16 + quad * 4;
#pragma unroll
    for (int nt = 0; nt < 16; ++nt) {
      const float sdf = (nt < 8) ? sd0p : sd1p;
#pragma unroll
      for (int r = 0; r < 4; ++r)
        out[(m0 + rowl + r) * (size_t)HDIM + n0 + nt * 16 + l16] =
            acc[mt][nt][r] * prX[mt][r] * sdf;
    }
  }
}

// ---------------------------------------------------------------------------
extern "C" void kernel_launch(void* const* d_in, const int* in_sizes, int n_in,
                              void* d_out, int out_size, void* d_ws, size_t ws_size,
                              hipStream_t stream) {
  const float* x   = (const float*)d_in[0];
  const void* gw_s = d_in[1];
  const float* gs  = (const float*)d_in[2];
  const void* uw_s = d_in[3];
  const float* us  = (const float*)d_in[4];
  const void* dw_s = d_in[5];
  const float* dsc = (const float*)d_in[6];
  float* out       = (float*)d_out;

  const size_t NW = (size_t)IDIM * HDIM;  // 58,720,256 elements per weight

  unsigned char* ws = (unsigned char*)d_ws;
  unsigned char* xq = ws;                         // 16 MB
  float* xsT = (float*)(ws + 16777216);           // 512 KB
  unsigned char* hq  = ws + 17301504;             // 56 MB
  float* hsT = (float*)(ws + 76021760);           // 1.75 MB
  unsigned char* gwq = ws + 77856768;             // 56 MB
  unsigned char* uwq = ws + 136577024;            // 56 MB
  unsigned char* dwq = gwq;                       // reuse gate slot after dual_gemm
  int* flag = (int*)(ws + 195297280);

  const bool fits = ws_size >= (size_t)195297284;
  const int use_conv = fits ? 1 : 0;

  const int convBlocks = (int)(NW / (16 * 256));  // 14336, exact

  if (fits) {
    detect_dtype<<<1, 64, 0, stream>>>((const unsigned int*)gw_s, flag);
    conv_w<<<convBlocks, 256, 0, stream>>>(gw_s, gwq, flag);
    conv_w<<<convBlocks, 256, 0, stream>>>(uw_s, uwq, flag);
  }
  fq_act<<<(MDIM * (HDIM / 128)) / 4, 256, 0, stream>>>(x, xq, xsT);
  dual_gemm_silu_fq<<<(MDIM / 128) * (IDIM / 128), 256, 0, stream>>>(
      xq, xsT, gwq, (const unsigned char*)gw_s, gs,
      uwq, (const unsigned char*)uw_s, us, hq, hsT, flag, use_conv);
  if (fits) {
    conv_w<<<convBlocks, 256, 0, stream>>>(dw_s, dwq, flag);
  }
  gemm_down<<<(MDIM / 128) * (HDIM / 256), 256, 0, stream>>>(
      hq, hsT, dwq, (const unsigned char*)dw_s, dsc, out, flag, use_conv);
}